// Round 3
// baseline (350.202 us; speedup 1.0000x reference)
//
#include <hip/hip_runtime.h>
#include <hip/hip_bf16.h>

#define N_NODES 100000
#define N_EDGES 1600000
#define N_AGENTS 1000

#define NB 782                 // buckets of 128 nodes (782*128 = 100096 >= 100000)
#define CONV_BLOCKS 3125       // 800000 float4->ushort4 elements / 256
#define WCAT_BLOCKS 24         // 6144 / 256
#define FLAGS_I4 25024         // 100096 ints / 4
#define FLAG_BLOCKS 98
#define NCLS_I4 100096         // 400384 ints / 4
#define NCLS_BLOCKS 391        // 100096 / 256 exactly
#define HIST_BLOCKS 1024
#define SCAT_BLOCKS 2048

typedef short s16x8 __attribute__((ext_vector_type(8)));
typedef float f32x4 __attribute__((ext_vector_type(4)));

// float -> bf16 round-to-nearest-even
__device__ __forceinline__ unsigned short f2bf(float f) {
    unsigned u = __float_as_uint(f);
    u += 0x7fffu + ((u >> 16) & 1u);
    return (unsigned short)(u >> 16);
}
__device__ __forceinline__ float bflo(unsigned u) { return __uint_as_float(u << 16); }
__device__ __forceinline__ float bfhi(unsigned u) { return __uint_as_float(u & 0xffff0000u); }

// ---------------- D1: prep — x conv, Wcat conv, zero flags/nodecls/tot ----------------
__global__ __launch_bounds__(256) void prep_kernel(
    const float* __restrict__ x, unsigned short* __restrict__ xb,
    const float* __restrict__ Wl1, const float* __restrict__ Wr1,
    const float* __restrict__ Wl2, const float* __restrict__ Wr2,
    const float* __restrict__ Wl3, const float* __restrict__ Wr3,
    unsigned short* __restrict__ Wcat, int* __restrict__ flags,
    int* __restrict__ nodecls, int* __restrict__ tot)
{
    int b = blockIdx.x;
    if (b < CONV_BLOCKS) {
        int i = b * 256 + threadIdx.x;                   // exact: 800000 elements
        float4 v = ((const float4*)x)[i];
        ((ushort4*)xb)[i] = make_ushort4(f2bf(v.x), f2bf(v.y), f2bf(v.z), f2bf(v.w));
    } else if (b < CONV_BLOCKS + WCAT_BLOCKS) {
        int gid = (b - CONV_BLOCKS) * 256 + threadIdx.x; // 6144 exact
        int L = gid >> 11, idx = gid & 2047;
        int k = idx >> 5, n = idx & 31;
        const float* Wl = (L == 0) ? Wl1 : (L == 1) ? Wl2 : Wl3;
        const float* Wr = (L == 0) ? Wr1 : (L == 1) ? Wr2 : Wr3;
        float v = (k < 32) ? Wl[k * 32 + n] : Wr[(k - 32) * 32 + n];
        Wcat[gid] = f2bf(v);
    } else if (b < CONV_BLOCKS + WCAT_BLOCKS + FLAG_BLOCKS) {
        int gid = (b - CONV_BLOCKS - WCAT_BLOCKS) * 256 + threadIdx.x;
        if (gid < FLAGS_I4) ((int4*)flags)[gid] = make_int4(0, 0, 0, 0);
    } else if (b < CONV_BLOCKS + WCAT_BLOCKS + FLAG_BLOCKS + NCLS_BLOCKS) {
        int gid = (b - CONV_BLOCKS - WCAT_BLOCKS - FLAG_BLOCKS) * 256 + threadIdx.x;
        ((int4*)nodecls)[gid] = make_int4(0, 0, 0, 0);   // 100096 exact
    } else {
        for (int i = threadIdx.x; i < 800; i += 256) tot[i] = 0;
    }
}

// ---------------- D2: per-(node,class) histogram (global atomics) + bucket totals ----------------
__global__ __launch_bounds__(256) void hist_kernel(
    const int* __restrict__ src, const int* __restrict__ dst,
    int* __restrict__ nodecls, int* __restrict__ tot)
{
    __shared__ int h[NB];
    for (int i = threadIdx.x; i < NB; i += 256) h[i] = 0;
    __syncthreads();
    for (int e = blockIdx.x * 256 + threadIdx.x; e < N_EDGES; e += HIST_BLOCKS * 256) {
        int d = dst[e], s = src[e];
        atomicAdd(&nodecls[(d << 2) | (s >> 15)], 1);    // fire-and-forget global atomic
        atomicAdd(&h[d >> 7], 1);                        // LDS atomic
    }
    __syncthreads();
    for (int i = threadIdx.x; i < NB; i += 256)
        if (h[i]) atomicAdd(&tot[i], h[i]);
}

// ---------------- D3: per-bucket scan -> absolute cursors (in-place) + packed rowptr ----------------
// Block b: (1) inline exclusive scan of tot[0..NB) -> bucket base; (2) scan its
// 512 (node,class) counters; overwrite nodecls with absolute scatter cursors;
// (3) pk[node] = (absolute beg << 11) | count  (count < 2048 always here).
__global__ __launch_bounds__(256) void nodescan_kernel(
    const int* __restrict__ tot, int* __restrict__ cur4,
    unsigned* __restrict__ pk, int* __restrict__ flags)
{
    __shared__ int tsum[256], incl[256], sS[256];
    __shared__ int sbase;
    int b = blockIdx.x, t = threadIdx.x;

    // ---- scan bucket totals to find this bucket's absolute start ----
    int i0 = t * 4;
    int v0 = (i0     < NB) ? tot[i0]     : 0;
    int v1 = (i0 + 1 < NB) ? tot[i0 + 1] : 0;
    int v2 = (i0 + 2 < NB) ? tot[i0 + 2] : 0;
    int v3 = (i0 + 3 < NB) ? tot[i0 + 3] : 0;
    int p1 = v0, p2 = v0 + v1, p3 = v0 + v1 + v2, s4 = p3 + v3;
    tsum[t] = s4;
    __syncthreads();
    for (int off = 1; off < 256; off <<= 1) {
        int u = (t >= off) ? tsum[t - off] : 0;
        __syncthreads();
        tsum[t] += u;
        __syncthreads();
    }
    if ((b >> 2) == t) {
        int excl = tsum[t] - s4;
        int o = b & 3;
        sbase = excl + (o == 0 ? 0 : o == 1 ? p1 : o == 2 ? p2 : p3);
    }
    __syncthreads();
    int base = sbase;

    // ---- scan own 512 counters (2 per thread) ----
    int2 ab = ((const int2*)(cur4 + (size_t)b * 512))[t];
    int a = ab.x, c = ab.y;
    int s2 = a + c;
    incl[t] = s2; sS[t] = s2;
    __syncthreads();
    for (int off = 1; off < 256; off <<= 1) {
        int u = (t >= off) ? incl[t - off] : 0;
        __syncthreads();
        incl[t] += u;
        __syncthreads();
    }
    int eprev = incl[t] - s2;                            // exclusive before counter 2t
    ((int2*)(cur4 + (size_t)b * 512))[t] = make_int2(base + eprev, base + eprev + a);
    __syncthreads();
    if (t < 128) {
        int e0 = incl[2 * t] - sS[2 * t];                // exclusive before counter 4t
        int cnt = incl[2 * t + 1] - e0;                  // node t's total degree
        unsigned beg = (unsigned)(base + e0);
        int node = b * 128 + t;
        pk[node] = (beg << 11) | (unsigned)min(cnt, 2047);
        if (node < N_AGENTS) flags[node] = 1;            // agents are layer-2 active
    }
}

// ---------------- D4: scatter edges directly to final sorted esrc ----------------
__global__ __launch_bounds__(256) void scatter_kernel(
    const int* __restrict__ src, const int* __restrict__ dst,
    int* __restrict__ cur4, int* __restrict__ esrc, int* __restrict__ flags)
{
    for (int e = blockIdx.x * 256 + threadIdx.x; e < N_EDGES; e += SCAT_BLOCKS * 256) {
        int d = dst[e], s = src[e];
        int slot = atomicAdd(&cur4[(d << 2) | (s >> 15)], 1);
        esrc[slot] = s;
        if (d < N_AGENTS) flags[s] = 1;                  // agents' in-neighbors
    }
}

// ---------------- fused layer: aggregate (regs) -> LDS -> MFMA dense -> out ----------------
// Block = 64 nodes. Phase 1: 4 lanes/node, lane owns 8 channels, fp32 acc over
// all neighbors (src-class-ordered -> L2-friendly); pk[node] packs (beg<<11|cnt).
// Phase 2: wave w MFMAs nodes [w*16, w*16+16); weights in LDS.
// final=1: layer-3 + 32->8 output projection through a second LDS stage.
__global__ __launch_bounds__(256) void sage_fused_kernel(
    const unsigned* __restrict__ pk, const int* __restrict__ esrc,
    const unsigned short* __restrict__ hb,
    const unsigned short* __restrict__ Wcat, const float* __restrict__ bl,
    const float* __restrict__ Wout, const float* __restrict__ bout,
    void* __restrict__ outp, int n_nodes, int final)
{
    __shared__ unsigned short sW[2048];      // 64k x 32n bf16 layer weights
    __shared__ float sb[32];
    __shared__ unsigned short smean[64 * 40];
    __shared__ float sh3[64 * 33];
    __shared__ float sWo[256];
    __shared__ float sbo[8];

    int tid = threadIdx.x;
    ((uint4*)sW)[tid] = ((const uint4*)Wcat)[tid];       // 256 x 16B = 4KB exact
    if (tid < 32) sb[tid] = bl[tid];
    if (final) {
        sWo[tid] = Wout[tid];                            // 256 exact
        if (tid < 8) sbo[tid] = bout[tid];
    }

    int lane = tid & 63, wave = tid >> 6;

    // ---- phase 1: aggregate ----
    int g = lane >> 2, q = lane & 3;
    int nodeA = blockIdx.x * 64 + wave * 16 + g;
    int beg = 0, cnt = 0;
    if (nodeA < n_nodes) {
        unsigned pkv = pk[nodeA];
        beg = (int)(pkv >> 11);
        cnt = (int)(pkv & 2047u);
    }
    int end = beg + cnt;
    float a0 = 0.f, a1 = 0.f, a2 = 0.f, a3 = 0.f;
    float a4 = 0.f, a5 = 0.f, a6 = 0.f, a7 = 0.f;
    int j = beg;
    for (; j + 3 < end; j += 4) {
        int s0 = esrc[j];
        int s1 = esrc[j + 1];
        int s2 = esrc[j + 2];
        int s3 = esrc[j + 3];
        uint4 u0 = *(const uint4*)(hb + s0 * 32 + q * 8);
        uint4 u1 = *(const uint4*)(hb + s1 * 32 + q * 8);
        uint4 u2 = *(const uint4*)(hb + s2 * 32 + q * 8);
        uint4 u3 = *(const uint4*)(hb + s3 * 32 + q * 8);
        a0 += bflo(u0.x); a1 += bfhi(u0.x);
        a2 += bflo(u0.y); a3 += bfhi(u0.y);
        a4 += bflo(u0.z); a5 += bfhi(u0.z);
        a6 += bflo(u0.w); a7 += bfhi(u0.w);
        a0 += bflo(u1.x); a1 += bfhi(u1.x);
        a2 += bflo(u1.y); a3 += bfhi(u1.y);
        a4 += bflo(u1.z); a5 += bfhi(u1.z);
        a6 += bflo(u1.w); a7 += bfhi(u1.w);
        a0 += bflo(u2.x); a1 += bfhi(u2.x);
        a2 += bflo(u2.y); a3 += bfhi(u2.y);
        a4 += bflo(u2.z); a5 += bfhi(u2.z);
        a6 += bflo(u2.w); a7 += bfhi(u2.w);
        a0 += bflo(u3.x); a1 += bfhi(u3.x);
        a2 += bflo(u3.y); a3 += bfhi(u3.y);
        a4 += bflo(u3.z); a5 += bfhi(u3.z);
        a6 += bflo(u3.w); a7 += bfhi(u3.w);
    }
    for (; j < end; j++) {
        int s = esrc[j];
        uint4 u = *(const uint4*)(hb + s * 32 + q * 8);
        a0 += bflo(u.x); a1 += bfhi(u.x);
        a2 += bflo(u.y); a3 += bfhi(u.y);
        a4 += bflo(u.z); a5 += bfhi(u.z);
        a6 += bflo(u.w); a7 += bfhi(u.w);
    }
    float iv = 1.0f / fmaxf((float)cnt, 1.0f);
    uint4 o;
    o.x = (unsigned)f2bf(a0 * iv) | ((unsigned)f2bf(a1 * iv) << 16);
    o.y = (unsigned)f2bf(a2 * iv) | ((unsigned)f2bf(a3 * iv) << 16);
    o.z = (unsigned)f2bf(a4 * iv) | ((unsigned)f2bf(a5 * iv) << 16);
    o.w = (unsigned)f2bf(a6 * iv) | ((unsigned)f2bf(a7 * iv) << 16);
    int mrow = wave * 16 + g;
    *(uint4*)&smean[mrow * 40 + q * 8] = o;
    __syncthreads();

    // ---- phase 2: dense via MFMA ----
    int l15 = lane & 15, quad = lane >> 4;
    s16x8 bf_[2][2];
    #pragma unroll
    for (int kt = 0; kt < 2; kt++)
        #pragma unroll
        for (int nt = 0; nt < 2; nt++)
            #pragma unroll
            for (int jj = 0; jj < 8; jj++) {
                int k = kt * 32 + quad * 8 + jj;
                bf_[kt][nt][jj] = (short)sW[k * 32 + l15 + nt * 16];
            }
    float bias0 = sb[l15], bias1 = sb[l15 + 16];

    int tilebase = blockIdx.x * 64 + wave * 16;
    int nodeD = tilebase + l15;
    int na = min(nodeD, n_nodes - 1);
    s16x8 am = *(const s16x8*)&smean[(wave * 16 + l15) * 40 + quad * 8];
    s16x8 as = *(const s16x8*)(hb + (size_t)na * 32 + quad * 8);
    f32x4 acc0 = {0.f, 0.f, 0.f, 0.f};
    f32x4 acc1 = {0.f, 0.f, 0.f, 0.f};
    acc0 = __builtin_amdgcn_mfma_f32_16x16x32_bf16(am, bf_[0][0], acc0, 0, 0, 0);
    acc0 = __builtin_amdgcn_mfma_f32_16x16x32_bf16(as, bf_[1][0], acc0, 0, 0, 0);
    acc1 = __builtin_amdgcn_mfma_f32_16x16x32_bf16(am, bf_[0][1], acc1, 0, 0, 0);
    acc1 = __builtin_amdgcn_mfma_f32_16x16x32_bf16(as, bf_[1][1], acc1, 0, 0, 0);

    if (!final) {
        #pragma unroll
        for (int r = 0; r < 4; r++) {
            int onode = tilebase + quad * 4 + r;
            if (onode < n_nodes) {
                ((unsigned short*)outp)[onode * 32 + l15]      = f2bf(fmaxf(acc0[r] + bias0, 0.f));
                ((unsigned short*)outp)[onode * 32 + l15 + 16] = f2bf(fmaxf(acc1[r] + bias1, 0.f));
            }
        }
    } else {
        #pragma unroll
        for (int r = 0; r < 4; r++) {
            int row = wave * 16 + quad * 4 + r;
            sh3[row * 33 + l15]      = fmaxf(acc0[r] + bias0, 0.f);
            sh3[row * 33 + l15 + 16] = fmaxf(acc1[r] + bias1, 0.f);
        }
        __syncthreads();
        // 64 nodes x 8 out-channels = 512 outputs, 2 per thread
        #pragma unroll
        for (int i = tid; i < 512; i += 256) {
            int ln = i >> 3, c = i & 7;
            int gn = blockIdx.x * 64 + ln;
            if (gn < N_AGENTS) {
                float ov = sbo[c];
                #pragma unroll
                for (int k = 0; k < 32; k++) ov += sh3[ln * 33 + k] * sWo[k * 8 + c];
                ((float*)outp)[gn * 8 + c] = ov;
            }
        }
    }
}

// ---------------- fused layer 2: flag-gated over the full grid ----------------
__global__ __launch_bounds__(256) void sage_fused_flag_kernel(
    const unsigned* __restrict__ pk, const int* __restrict__ esrc,
    const unsigned short* __restrict__ hb,
    const unsigned short* __restrict__ Wcat, const float* __restrict__ bl,
    unsigned short* __restrict__ outp, const int* __restrict__ flags,
    int n_nodes)
{
    __shared__ unsigned short sW[2048];
    __shared__ float sb[32];
    __shared__ unsigned short smean[64 * 40];
    __shared__ int sflag[64];

    int tid = threadIdx.x;
    ((uint4*)sW)[tid] = ((const uint4*)Wcat)[tid];
    if (tid < 32) sb[tid] = bl[tid];
    if (tid < 64) {
        int gid = blockIdx.x * 64 + tid;
        sflag[tid] = (gid < n_nodes) ? flags[gid] : 0;
    }
    __syncthreads();

    int lane = tid & 63, wave = tid >> 6;

    // ---- phase 1: aggregate (flagged nodes only) ----
    int g = lane >> 2, q = lane & 3;
    int lnode = wave * 16 + g;
    int nodeA = blockIdx.x * 64 + lnode;
    int beg = 0, cnt = 0;
    if (sflag[lnode]) {
        unsigned pkv = pk[nodeA];
        beg = (int)(pkv >> 11);
        cnt = (int)(pkv & 2047u);
    }
    int end = beg + cnt;
    float a0 = 0.f, a1 = 0.f, a2 = 0.f, a3 = 0.f;
    float a4 = 0.f, a5 = 0.f, a6 = 0.f, a7 = 0.f;
    int j = beg;
    for (; j + 3 < end; j += 4) {
        int s0 = esrc[j];
        int s1 = esrc[j + 1];
        int s2 = esrc[j + 2];
        int s3 = esrc[j + 3];
        uint4 u0 = *(const uint4*)(hb + s0 * 32 + q * 8);
        uint4 u1 = *(const uint4*)(hb + s1 * 32 + q * 8);
        uint4 u2 = *(const uint4*)(hb + s2 * 32 + q * 8);
        uint4 u3 = *(const uint4*)(hb + s3 * 32 + q * 8);
        a0 += bflo(u0.x); a1 += bfhi(u0.x);
        a2 += bflo(u0.y); a3 += bfhi(u0.y);
        a4 += bflo(u0.z); a5 += bfhi(u0.z);
        a6 += bflo(u0.w); a7 += bfhi(u0.w);
        a0 += bflo(u1.x); a1 += bfhi(u1.x);
        a2 += bflo(u1.y); a3 += bfhi(u1.y);
        a4 += bflo(u1.z); a5 += bfhi(u1.z);
        a6 += bflo(u1.w); a7 += bfhi(u1.w);
        a0 += bflo(u2.x); a1 += bfhi(u2.x);
        a2 += bflo(u2.y); a3 += bfhi(u2.y);
        a4 += bflo(u2.z); a5 += bfhi(u2.z);
        a6 += bflo(u2.w); a7 += bfhi(u2.w);
        a0 += bflo(u3.x); a1 += bfhi(u3.x);
        a2 += bflo(u3.y); a3 += bfhi(u3.y);
        a4 += bflo(u3.z); a5 += bfhi(u3.z);
        a6 += bflo(u3.w); a7 += bfhi(u3.w);
    }
    for (; j < end; j++) {
        int s = esrc[j];
        uint4 u = *(const uint4*)(hb + s * 32 + q * 8);
        a0 += bflo(u.x); a1 += bfhi(u.x);
        a2 += bflo(u.y); a3 += bfhi(u.y);
        a4 += bflo(u.z); a5 += bfhi(u.z);
        a6 += bflo(u.w); a7 += bfhi(u.w);
    }
    float iv = 1.0f / fmaxf((float)cnt, 1.0f);
    uint4 o;
    o.x = (unsigned)f2bf(a0 * iv) | ((unsigned)f2bf(a1 * iv) << 16);
    o.y = (unsigned)f2bf(a2 * iv) | ((unsigned)f2bf(a3 * iv) << 16);
    o.z = (unsigned)f2bf(a4 * iv) | ((unsigned)f2bf(a5 * iv) << 16);
    o.w = (unsigned)f2bf(a6 * iv) | ((unsigned)f2bf(a7 * iv) << 16);
    *(uint4*)&smean[lnode * 40 + q * 8] = o;
    __syncthreads();

    // ---- phase 2: dense via MFMA ----
    int l15 = lane & 15, quad = lane >> 4;
    s16x8 bf_[2][2];
    #pragma unroll
    for (int kt = 0; kt < 2; kt++)
        #pragma unroll
        for (int nt = 0; nt < 2; nt++)
            #pragma unroll
            for (int jj = 0; jj < 8; jj++) {
                int k = kt * 32 + quad * 8 + jj;
                bf_[kt][nt][jj] = (short)sW[k * 32 + l15 + nt * 16];
            }
    float bias0 = sb[l15], bias1 = sb[l15 + 16];

    int tilebase = blockIdx.x * 64 + wave * 16;
    int nodeD = tilebase + l15;
    int na = min(nodeD, n_nodes - 1);
    s16x8 am = *(const s16x8*)&smean[(wave * 16 + l15) * 40 + quad * 8];
    s16x8 as = *(const s16x8*)(hb + (size_t)na * 32 + quad * 8);
    f32x4 acc0 = {0.f, 0.f, 0.f, 0.f};
    f32x4 acc1 = {0.f, 0.f, 0.f, 0.f};
    acc0 = __builtin_amdgcn_mfma_f32_16x16x32_bf16(am, bf_[0][0], acc0, 0, 0, 0);
    acc0 = __builtin_amdgcn_mfma_f32_16x16x32_bf16(as, bf_[1][0], acc0, 0, 0, 0);
    acc1 = __builtin_amdgcn_mfma_f32_16x16x32_bf16(am, bf_[0][1], acc1, 0, 0, 0);
    acc1 = __builtin_amdgcn_mfma_f32_16x16x32_bf16(as, bf_[1][1], acc1, 0, 0, 0);

    #pragma unroll
    for (int r = 0; r < 4; r++) {
        int lr = wave * 16 + quad * 4 + r;
        int onode = tilebase + quad * 4 + r;
        if (onode < n_nodes && sflag[lr]) {
            outp[onode * 32 + l15]      = f2bf(fmaxf(acc0[r] + bias0, 0.f));
            outp[onode * 32 + l15 + 16] = f2bf(fmaxf(acc1[r] + bias1, 0.f));
        }
    }
}

extern "C" void kernel_launch(void* const* d_in, const int* in_sizes, int n_in,
                              void* d_out, int out_size, void* d_ws, size_t ws_size,
                              hipStream_t stream) {
    const float* x   = (const float*)d_in[0];
    const int* ei    = (const int*)d_in[1];
    const float* Wl1 = (const float*)d_in[2];
    const float* bl1 = (const float*)d_in[3];
    const float* Wr1 = (const float*)d_in[4];
    const float* Wl2 = (const float*)d_in[5];
    const float* bl2 = (const float*)d_in[6];
    const float* Wr2 = (const float*)d_in[7];
    const float* Wl3 = (const float*)d_in[8];
    const float* bl3 = (const float*)d_in[9];
    const float* Wr3 = (const float*)d_in[10];
    const float* Wout = (const float*)d_in[11];
    const float* bout = (const float*)d_in[12];
    float* out = (float*)d_out;

    const int* src = ei;
    const int* dst = ei + N_EDGES;

    // workspace layout
    char* ws = (char*)d_ws;
    int*      nodecls = (int*)ws;                              ws += (size_t)NB * 512 * 4;   // aliased as cur4 after nodescan
    int*      tot     = (int*)ws;                              ws += 800 * 4;
    unsigned* pk      = (unsigned*)ws;                         ws += (size_t)100096 * 4;
    int*      esrc    = (int*)ws;                              ws += (size_t)N_EDGES * 4;
    unsigned short* hXb  = (unsigned short*)ws;                ws += (size_t)N_NODES * 32 * 2;
    unsigned short* hAb  = (unsigned short*)ws;                ws += (size_t)N_NODES * 32 * 2;
    unsigned short* hBb  = (unsigned short*)ws;                ws += (size_t)N_NODES * 32 * 2;
    unsigned short* Wcat = (unsigned short*)ws;                ws += 3 * 2048 * 2;
    int*      flags   = (int*)ws;                              ws += (size_t)100096 * 4;

    // ---- build: 4 dispatches, 2 edge passes, no ebuf round-trip ----
    prep_kernel<<<CONV_BLOCKS + WCAT_BLOCKS + FLAG_BLOCKS + NCLS_BLOCKS + 1, 256, 0, stream>>>(
        x, hXb, Wl1, Wr1, Wl2, Wr2, Wl3, Wr3, Wcat, flags, nodecls, tot);
    hist_kernel<<<HIST_BLOCKS, 256, 0, stream>>>(src, dst, nodecls, tot);
    nodescan_kernel<<<NB, 256, 0, stream>>>(tot, nodecls, pk, flags);
    scatter_kernel<<<SCAT_BLOCKS, 256, 0, stream>>>(src, dst, nodecls, esrc, flags);

    // ---- fused layers: 3 dispatches ----
    sage_fused_kernel<<<(N_NODES + 63) / 64, 256, 0, stream>>>(
        pk, esrc, hXb, Wcat, bl1, Wout, bout, hAb, N_NODES, 0);
    sage_fused_flag_kernel<<<(N_NODES + 63) / 64, 256, 0, stream>>>(
        pk, esrc, hAb, Wcat + 2048, bl2, hBb, flags, N_NODES);
    sage_fused_kernel<<<(N_AGENTS + 63) / 64, 256, 0, stream>>>(
        pk, esrc, hBb, Wcat + 4096, bl3, Wout, bout, out, N_AGENTS, 1);
}

// Round 4
// 177.529 us; speedup vs baseline: 1.9727x; 1.9727x over previous
//
#include <hip/hip_runtime.h>
#include <hip/hip_bf16.h>

#define N_NODES 100000
#define N_EDGES 1600000
#define N_AGENTS 1000

#define NB 782                 // buckets of 128 nodes (782*128 = 100096 >= 100000)
#define ABLK 512               // edge-chunk blocks for histogram/scatter
#define CHUNK (N_EDGES / ABLK) // 3125 exactly
#define CONV_BLOCKS 3125       // 800000 float4->ushort4 elements / 256
#define FLAGS_I4 25024         // 100096 ints / 4
#define FLAG_BLOCKS 98         // 25024 / 256 (rounded up)

typedef short s16x8 __attribute__((ext_vector_type(8)));
typedef float f32x4 __attribute__((ext_vector_type(4)));

// float -> bf16 round-to-nearest-even
__device__ __forceinline__ unsigned short f2bf(float f) {
    unsigned u = __float_as_uint(f);
    u += 0x7fffu + ((u >> 16) & 1u);
    return (unsigned short)(u >> 16);
}
__device__ __forceinline__ float bflo(unsigned u) { return __uint_as_float(u << 16); }
__device__ __forceinline__ float bfhi(unsigned u) { return __uint_as_float(u & 0xffff0000u); }

// ---------------- A: bucket histogram (LDS atomics only) + fused prep ----------------
__global__ __launch_bounds__(256) void hist_prep_kernel(
    const int* __restrict__ dst, int* __restrict__ partialT,
    const float* __restrict__ x, unsigned short* __restrict__ xb,
    const float* __restrict__ Wl1, const float* __restrict__ Wr1,
    const float* __restrict__ Wl2, const float* __restrict__ Wr2,
    const float* __restrict__ Wl3, const float* __restrict__ Wr3,
    unsigned short* __restrict__ Wcat, int* __restrict__ flags)
{
    int b = blockIdx.x;
    if (b < ABLK) {
        __shared__ int hist[NB];
        for (int i = threadIdx.x; i < NB; i += 256) hist[i] = 0;
        __syncthreads();
        int beg = b * CHUNK;
        for (int e = beg + threadIdx.x; e < beg + CHUNK; e += 256)
            atomicAdd(&hist[dst[e] >> 7], 1);            // LDS atomic
        __syncthreads();
        for (int i = threadIdx.x; i < NB; i += 256) partialT[i * ABLK + b] = hist[i];
    } else if (b < ABLK + CONV_BLOCKS) {
        int i = (b - ABLK) * 256 + threadIdx.x;          // exact: 800000 elements
        float4 v = ((const float4*)x)[i];
        ((ushort4*)xb)[i] = make_ushort4(f2bf(v.x), f2bf(v.y), f2bf(v.z), f2bf(v.w));
    } else if (b < ABLK + CONV_BLOCKS + 24) {
        int gid = (b - ABLK - CONV_BLOCKS) * 256 + threadIdx.x;  // 6144 exact
        int L = gid >> 11, idx = gid & 2047;
        int k = idx >> 5, n = idx & 31;
        const float* Wl = (L == 0) ? Wl1 : (L == 1) ? Wl2 : Wl3;
        const float* Wr = (L == 0) ? Wr1 : (L == 1) ? Wr2 : Wr3;
        float v = (k < 32) ? Wl[k * 32 + n] : Wr[(k - 32) * 32 + n];
        Wcat[gid] = f2bf(v);
    } else {
        int gid = (b - ABLK - CONV_BLOCKS - 24) * 256 + threadIdx.x;
        if (gid < FLAGS_I4) ((int4*)flags)[gid] = make_int4(0, 0, 0, 0);
    }
}

// ---------------- B1: per-bucket prefix over ABLK chunk-partials (1 wave/bucket) ----------------
__global__ __launch_bounds__(256) void bucket_prefix_kernel(
    const int* __restrict__ partialT, int* __restrict__ baseT, int* __restrict__ tot)
{
    int wave = threadIdx.x >> 6, lane = threadIdx.x & 63;
    int t = blockIdx.x * 4 + wave;
    if (t >= NB) return;
    const int4* p = (const int4*)(partialT + (size_t)t * ABLK);
    int4 u0 = p[lane * 2], u1 = p[lane * 2 + 1];        // 8 partials per lane
    int v0 = u0.x, v1 = u0.y, v2 = u0.z, v3 = u0.w;
    int v4 = u1.x, v5 = u1.y, v6 = u1.z, v7 = u1.w;
    int p0 = 0, p1 = v0, p2 = p1 + v1, p3 = p2 + v2;
    int p4 = p3 + v3, p5 = p4 + v4, p6 = p5 + v5, p7 = p6 + v6;
    int s = p7 + v7;                                     // lane total
    int x = s;                                           // wave inclusive scan
    #pragma unroll
    for (int off = 1; off < 64; off <<= 1) {
        int y = __shfl_up(x, off);
        if (lane >= off) x += y;
    }
    int excl = x - s;                                    // exclusive prefix of lane sums
    int4* q = (int4*)(baseT + (size_t)t * ABLK);
    q[lane * 2]     = make_int4(excl + p0, excl + p1, excl + p2, excl + p3);
    q[lane * 2 + 1] = make_int4(excl + p4, excl + p5, excl + p6, excl + p7);
    if (lane == 63) tot[t] = x;
}

// ---------------- C: scatter edges into buckets (inlined totals-scan) ----------------
// Each block scans tot[0..NB) in LDS to get bucket starts; block 0 also
// publishes bstart[] for bucket_csr_kernel.
__global__ __launch_bounds__(256) void bucket_scatter_kernel(
    const int* __restrict__ src, const int* __restrict__ dst,
    const int* __restrict__ baseT, const int* __restrict__ tot,
    int* __restrict__ bstart, int* __restrict__ ebuf)
{
    __shared__ int cur[NB];
    __shared__ int tsum[256];
    int b = blockIdx.x, t = threadIdx.x;
    int i0 = t * 4;
    int v0 = (i0     < NB) ? tot[i0]     : 0;
    int v1 = (i0 + 1 < NB) ? tot[i0 + 1] : 0;
    int v2 = (i0 + 2 < NB) ? tot[i0 + 2] : 0;
    int v3 = (i0 + 3 < NB) ? tot[i0 + 3] : 0;
    int p1 = v0, p2 = v0 + v1, p3 = v0 + v1 + v2, s4 = p3 + v3;
    tsum[t] = s4;
    __syncthreads();
    for (int off = 1; off < 256; off <<= 1) {
        int u = (t >= off) ? tsum[t - off] : 0;
        __syncthreads();
        tsum[t] += u;
        __syncthreads();
    }
    int excl = tsum[t] - s4;
    int st0 = excl, st1 = excl + p1, st2 = excl + p2, st3 = excl + p3;
    if (i0     < NB) cur[i0]     = st0 + baseT[(size_t)i0 * ABLK + b];
    if (i0 + 1 < NB) cur[i0 + 1] = st1 + baseT[(size_t)(i0 + 1) * ABLK + b];
    if (i0 + 2 < NB) cur[i0 + 2] = st2 + baseT[(size_t)(i0 + 2) * ABLK + b];
    if (i0 + 3 < NB) cur[i0 + 3] = st3 + baseT[(size_t)(i0 + 3) * ABLK + b];
    if (b == 0) {
        if (i0     < NB) bstart[i0]     = st0;
        if (i0 + 1 < NB) bstart[i0 + 1] = st1;
        if (i0 + 2 < NB) bstart[i0 + 2] = st2;
        if (i0 + 3 < NB) bstart[i0 + 3] = st3;
        if (t == 255)    bstart[NB] = tsum[255];         // == N_EDGES
    }
    __syncthreads();
    int beg = b * CHUNK;
    for (int e = beg + threadIdx.x; e < beg + CHUNK; e += 256) {
        int d = dst[e];
        int slot = atomicAdd(&cur[d >> 7], 1);           // LDS atomic
        ebuf[slot] = src[e] | ((d & 127) << 17);         // src < 2^17
    }
}

// ---------------- D: per-bucket CSR finalize + layer-2 active-set flagging ----------------
// Writes pk[node] = (absolute beg << 11) | degree  (beg < 2^21, deg <= 2047).
// Buckets 0..7 hold agent nodes: flag their edges' src + the agents themselves.
__global__ __launch_bounds__(256) void bucket_csr_kernel(
    const int* __restrict__ bstart, const int* __restrict__ ebuf,
    unsigned* __restrict__ pk, int* __restrict__ esrc,
    int* __restrict__ flags)
{
    __shared__ int hist4[512], cur4[512], tmp[256];
    int b = blockIdx.x;
    int t = threadIdx.x;
    int beg = bstart[b], end = bstart[b + 1];
    hist4[t] = 0; hist4[t + 256] = 0;
    __syncthreads();
    for (int i = beg + t; i < end; i += 256) {
        int p = ebuf[i];
        int ln = (p >> 17) & 127;
        int cls = (p & 0x1FFFF) >> 15;                   // 0..3
        atomicAdd(&hist4[ln * 4 + cls], 1);              // LDS atomic
    }
    __syncthreads();
    int c0 = 0, c1 = 0, c2 = 0, c3 = 0, v = 0;
    if (t < 128) {
        c0 = hist4[t * 4 + 0]; c1 = hist4[t * 4 + 1];
        c2 = hist4[t * 4 + 2]; c3 = hist4[t * 4 + 3];
        v = c0 + c1 + c2 + c3;
    }
    tmp[t] = v;
    __syncthreads();
    for (int off = 1; off < 256; off <<= 1) {
        int u = (t >= off) ? tmp[t - off] : 0;
        __syncthreads();
        tmp[t] += u;
        __syncthreads();
    }
    int excl = tmp[t] - v;                               // exclusive within bucket
    int node = b * 128 + t;
    if (t < 128 && node < N_NODES) {
        int start = beg + excl;
        pk[node] = ((unsigned)start << 11) | (unsigned)min(v, 2047);
        cur4[t * 4 + 0] = start;
        cur4[t * 4 + 1] = start + c0;
        cur4[t * 4 + 2] = start + c0 + c1;
        cur4[t * 4 + 3] = start + c0 + c1 + c2;
        if (node < N_AGENTS) flags[node] = 1;            // agents are active
    }
    __syncthreads();
    bool agent_bucket = (b < 8);                         // nodes 0..1023
    for (int i = beg + t; i < end; i += 256) {
        int p = ebuf[i];
        int ln = (p >> 17) & 127;
        int s = p & 0x1FFFF;
        int slot = atomicAdd(&cur4[ln * 4 + (s >> 15)], 1);  // LDS atomic
        esrc[slot] = s;
        if (agent_bucket && (b * 128 + ln) < N_AGENTS)
            flags[s] = 1;                                // agents' in-neighbors
    }
}

// ---------------- fused layer: aggregate (regs) -> LDS -> MFMA dense -> out ----------------
// Block = 64 nodes. Phase 1: 4 lanes/node, lane owns 8 channels, fp32 acc over
// all neighbors (src-class-ordered -> L2-friendly); pk[node] packs (beg<<11|cnt).
// Phase 2: wave w MFMAs nodes [w*16, w*16+16); weights in LDS.
// final=1: layer-3 + 32->8 output projection through a second LDS stage.
__global__ __launch_bounds__(256) void sage_fused_kernel(
    const unsigned* __restrict__ pk, const int* __restrict__ esrc,
    const unsigned short* __restrict__ hb,
    const unsigned short* __restrict__ Wcat, const float* __restrict__ bl,
    const float* __restrict__ Wout, const float* __restrict__ bout,
    void* __restrict__ outp, int n_nodes, int final)
{
    __shared__ unsigned short sW[2048];      // 64k x 32n bf16 layer weights
    __shared__ float sb[32];
    __shared__ unsigned short smean[64 * 40];
    __shared__ float sh3[64 * 33];
    __shared__ float sWo[256];
    __shared__ float sbo[8];

    int tid = threadIdx.x;
    ((uint4*)sW)[tid] = ((const uint4*)Wcat)[tid];       // 256 x 16B = 4KB exact
    if (tid < 32) sb[tid] = bl[tid];
    if (final) {
        sWo[tid] = Wout[tid];                            // 256 exact
        if (tid < 8) sbo[tid] = bout[tid];
    }

    int lane = tid & 63, wave = tid >> 6;

    // ---- phase 1: aggregate ----
    int g = lane >> 2, q = lane & 3;
    int nodeA = blockIdx.x * 64 + wave * 16 + g;
    int beg = 0, cnt = 0;
    if (nodeA < n_nodes) {
        unsigned pkv = pk[nodeA];
        beg = (int)(pkv >> 11);
        cnt = (int)(pkv & 2047u);
    }
    int end = beg + cnt;
    float a0 = 0.f, a1 = 0.f, a2 = 0.f, a3 = 0.f;
    float a4 = 0.f, a5 = 0.f, a6 = 0.f, a7 = 0.f;
    int j = beg;
    for (; j + 3 < end; j += 4) {
        int s0 = esrc[j];
        int s1 = esrc[j + 1];
        int s2 = esrc[j + 2];
        int s3 = esrc[j + 3];
        uint4 u0 = *(const uint4*)(hb + s0 * 32 + q * 8);
        uint4 u1 = *(const uint4*)(hb + s1 * 32 + q * 8);
        uint4 u2 = *(const uint4*)(hb + s2 * 32 + q * 8);
        uint4 u3 = *(const uint4*)(hb + s3 * 32 + q * 8);
        a0 += bflo(u0.x); a1 += bfhi(u0.x);
        a2 += bflo(u0.y); a3 += bfhi(u0.y);
        a4 += bflo(u0.z); a5 += bfhi(u0.z);
        a6 += bflo(u0.w); a7 += bfhi(u0.w);
        a0 += bflo(u1.x); a1 += bfhi(u1.x);
        a2 += bflo(u1.y); a3 += bfhi(u1.y);
        a4 += bflo(u1.z); a5 += bfhi(u1.z);
        a6 += bflo(u1.w); a7 += bfhi(u1.w);
        a0 += bflo(u2.x); a1 += bfhi(u2.x);
        a2 += bflo(u2.y); a3 += bfhi(u2.y);
        a4 += bflo(u2.z); a5 += bfhi(u2.z);
        a6 += bflo(u2.w); a7 += bfhi(u2.w);
        a0 += bflo(u3.x); a1 += bfhi(u3.x);
        a2 += bflo(u3.y); a3 += bfhi(u3.y);
        a4 += bflo(u3.z); a5 += bfhi(u3.z);
        a6 += bflo(u3.w); a7 += bfhi(u3.w);
    }
    for (; j < end; j++) {
        int s = esrc[j];
        uint4 u = *(const uint4*)(hb + s * 32 + q * 8);
        a0 += bflo(u.x); a1 += bfhi(u.x);
        a2 += bflo(u.y); a3 += bfhi(u.y);
        a4 += bflo(u.z); a5 += bfhi(u.z);
        a6 += bflo(u.w); a7 += bfhi(u.w);
    }
    float iv = 1.0f / fmaxf((float)cnt, 1.0f);
    uint4 o;
    o.x = (unsigned)f2bf(a0 * iv) | ((unsigned)f2bf(a1 * iv) << 16);
    o.y = (unsigned)f2bf(a2 * iv) | ((unsigned)f2bf(a3 * iv) << 16);
    o.z = (unsigned)f2bf(a4 * iv) | ((unsigned)f2bf(a5 * iv) << 16);
    o.w = (unsigned)f2bf(a6 * iv) | ((unsigned)f2bf(a7 * iv) << 16);
    int mrow = wave * 16 + g;
    *(uint4*)&smean[mrow * 40 + q * 8] = o;
    __syncthreads();

    // ---- phase 2: dense via MFMA ----
    int l15 = lane & 15, quad = lane >> 4;
    s16x8 bf_[2][2];
    #pragma unroll
    for (int kt = 0; kt < 2; kt++)
        #pragma unroll
        for (int nt = 0; nt < 2; nt++)
            #pragma unroll
            for (int jj = 0; jj < 8; jj++) {
                int k = kt * 32 + quad * 8 + jj;
                bf_[kt][nt][jj] = (short)sW[k * 32 + l15 + nt * 16];
            }
    float bias0 = sb[l15], bias1 = sb[l15 + 16];

    int tilebase = blockIdx.x * 64 + wave * 16;
    int nodeD = tilebase + l15;
    int na = min(nodeD, n_nodes - 1);
    s16x8 am = *(const s16x8*)&smean[(wave * 16 + l15) * 40 + quad * 8];
    s16x8 as = *(const s16x8*)(hb + (size_t)na * 32 + quad * 8);
    f32x4 acc0 = {0.f, 0.f, 0.f, 0.f};
    f32x4 acc1 = {0.f, 0.f, 0.f, 0.f};
    acc0 = __builtin_amdgcn_mfma_f32_16x16x32_bf16(am, bf_[0][0], acc0, 0, 0, 0);
    acc0 = __builtin_amdgcn_mfma_f32_16x16x32_bf16(as, bf_[1][0], acc0, 0, 0, 0);
    acc1 = __builtin_amdgcn_mfma_f32_16x16x32_bf16(am, bf_[0][1], acc1, 0, 0, 0);
    acc1 = __builtin_amdgcn_mfma_f32_16x16x32_bf16(as, bf_[1][1], acc1, 0, 0, 0);

    if (!final) {
        #pragma unroll
        for (int r = 0; r < 4; r++) {
            int onode = tilebase + quad * 4 + r;
            if (onode < n_nodes) {
                ((unsigned short*)outp)[onode * 32 + l15]      = f2bf(fmaxf(acc0[r] + bias0, 0.f));
                ((unsigned short*)outp)[onode * 32 + l15 + 16] = f2bf(fmaxf(acc1[r] + bias1, 0.f));
            }
        }
    } else {
        #pragma unroll
        for (int r = 0; r < 4; r++) {
            int row = wave * 16 + quad * 4 + r;
            sh3[row * 33 + l15]      = fmaxf(acc0[r] + bias0, 0.f);
            sh3[row * 33 + l15 + 16] = fmaxf(acc1[r] + bias1, 0.f);
        }
        __syncthreads();
        // 64 nodes x 8 out-channels = 512 outputs, 2 per thread
        #pragma unroll
        for (int i = tid; i < 512; i += 256) {
            int ln = i >> 3, c = i & 7;
            int gn = blockIdx.x * 64 + ln;
            if (gn < N_AGENTS) {
                float ov = sbo[c];
                #pragma unroll
                for (int k = 0; k < 32; k++) ov += sh3[ln * 33 + k] * sWo[k * 8 + c];
                ((float*)outp)[gn * 8 + c] = ov;
            }
        }
    }
}

// ---------------- fused layer 2: flag-gated over the full grid ----------------
// Only flagged nodes aggregate and store (inactive hBb rows stay poison --
// layer 3 never reads them). ~16.6k of 100k nodes active -> ~250k edges.
__global__ __launch_bounds__(256) void sage_fused_flag_kernel(
    const unsigned* __restrict__ pk, const int* __restrict__ esrc,
    const unsigned short* __restrict__ hb,
    const unsigned short* __restrict__ Wcat, const float* __restrict__ bl,
    unsigned short* __restrict__ outp, const int* __restrict__ flags,
    int n_nodes)
{
    __shared__ unsigned short sW[2048];
    __shared__ float sb[32];
    __shared__ unsigned short smean[64 * 40];
    __shared__ int sflag[64];

    int tid = threadIdx.x;
    ((uint4*)sW)[tid] = ((const uint4*)Wcat)[tid];
    if (tid < 32) sb[tid] = bl[tid];
    if (tid < 64) {
        int gid = blockIdx.x * 64 + tid;
        sflag[tid] = (gid < n_nodes) ? flags[gid] : 0;
    }
    __syncthreads();

    int lane = tid & 63, wave = tid >> 6;

    // ---- phase 1: aggregate (flagged nodes only) ----
    int g = lane >> 2, q = lane & 3;
    int lnode = wave * 16 + g;
    int nodeA = blockIdx.x * 64 + lnode;
    int beg = 0, cnt = 0;
    if (sflag[lnode]) {
        unsigned pkv = pk[nodeA];
        beg = (int)(pkv >> 11);
        cnt = (int)(pkv & 2047u);
    }
    int end = beg + cnt;
    float a0 = 0.f, a1 = 0.f, a2 = 0.f, a3 = 0.f;
    float a4 = 0.f, a5 = 0.f, a6 = 0.f, a7 = 0.f;
    int j = beg;
    for (; j + 3 < end; j += 4) {
        int s0 = esrc[j];
        int s1 = esrc[j + 1];
        int s2 = esrc[j + 2];
        int s3 = esrc[j + 3];
        uint4 u0 = *(const uint4*)(hb + s0 * 32 + q * 8);
        uint4 u1 = *(const uint4*)(hb + s1 * 32 + q * 8);
        uint4 u2 = *(const uint4*)(hb + s2 * 32 + q * 8);
        uint4 u3 = *(const uint4*)(hb + s3 * 32 + q * 8);
        a0 += bflo(u0.x); a1 += bfhi(u0.x);
        a2 += bflo(u0.y); a3 += bfhi(u0.y);
        a4 += bflo(u0.z); a5 += bfhi(u0.z);
        a6 += bflo(u0.w); a7 += bfhi(u0.w);
        a0 += bflo(u1.x); a1 += bfhi(u1.x);
        a2 += bflo(u1.y); a3 += bfhi(u1.y);
        a4 += bflo(u1.z); a5 += bfhi(u1.z);
        a6 += bflo(u1.w); a7 += bfhi(u1.w);
        a0 += bflo(u2.x); a1 += bfhi(u2.x);
        a2 += bflo(u2.y); a3 += bfhi(u2.y);
        a4 += bflo(u2.z); a5 += bfhi(u2.z);
        a6 += bflo(u2.w); a7 += bfhi(u2.w);
        a0 += bflo(u3.x); a1 += bfhi(u3.x);
        a2 += bflo(u3.y); a3 += bfhi(u3.y);
        a4 += bflo(u3.z); a5 += bfhi(u3.z);
        a6 += bflo(u3.w); a7 += bfhi(u3.w);
    }
    for (; j < end; j++) {
        int s = esrc[j];
        uint4 u = *(const uint4*)(hb + s * 32 + q * 8);
        a0 += bflo(u.x); a1 += bfhi(u.x);
        a2 += bflo(u.y); a3 += bfhi(u.y);
        a4 += bflo(u.z); a5 += bfhi(u.z);
        a6 += bflo(u.w); a7 += bfhi(u.w);
    }
    float iv = 1.0f / fmaxf((float)cnt, 1.0f);
    uint4 o;
    o.x = (unsigned)f2bf(a0 * iv) | ((unsigned)f2bf(a1 * iv) << 16);
    o.y = (unsigned)f2bf(a2 * iv) | ((unsigned)f2bf(a3 * iv) << 16);
    o.z = (unsigned)f2bf(a4 * iv) | ((unsigned)f2bf(a5 * iv) << 16);
    o.w = (unsigned)f2bf(a6 * iv) | ((unsigned)f2bf(a7 * iv) << 16);
    *(uint4*)&smean[lnode * 40 + q * 8] = o;
    __syncthreads();

    // ---- phase 2: dense via MFMA ----
    int l15 = lane & 15, quad = lane >> 4;
    s16x8 bf_[2][2];
    #pragma unroll
    for (int kt = 0; kt < 2; kt++)
        #pragma unroll
        for (int nt = 0; nt < 2; nt++)
            #pragma unroll
            for (int jj = 0; jj < 8; jj++) {
                int k = kt * 32 + quad * 8 + jj;
                bf_[kt][nt][jj] = (short)sW[k * 32 + l15 + nt * 16];
            }
    float bias0 = sb[l15], bias1 = sb[l15 + 16];

    int tilebase = blockIdx.x * 64 + wave * 16;
    int nodeD = tilebase + l15;
    int na = min(nodeD, n_nodes - 1);
    s16x8 am = *(const s16x8*)&smean[(wave * 16 + l15) * 40 + quad * 8];
    s16x8 as = *(const s16x8*)(hb + (size_t)na * 32 + quad * 8);
    f32x4 acc0 = {0.f, 0.f, 0.f, 0.f};
    f32x4 acc1 = {0.f, 0.f, 0.f, 0.f};
    acc0 = __builtin_amdgcn_mfma_f32_16x16x32_bf16(am, bf_[0][0], acc0, 0, 0, 0);
    acc0 = __builtin_amdgcn_mfma_f32_16x16x32_bf16(as, bf_[1][0], acc0, 0, 0, 0);
    acc1 = __builtin_amdgcn_mfma_f32_16x16x32_bf16(am, bf_[0][1], acc1, 0, 0, 0);
    acc1 = __builtin_amdgcn_mfma_f32_16x16x32_bf16(as, bf_[1][1], acc1, 0, 0, 0);

    #pragma unroll
    for (int r = 0; r < 4; r++) {
        int lr = wave * 16 + quad * 4 + r;
        int onode = tilebase + quad * 4 + r;
        if (onode < n_nodes && sflag[lr]) {
            outp[onode * 32 + l15]      = f2bf(fmaxf(acc0[r] + bias0, 0.f));
            outp[onode * 32 + l15 + 16] = f2bf(fmaxf(acc1[r] + bias1, 0.f));
        }
    }
}

extern "C" void kernel_launch(void* const* d_in, const int* in_sizes, int n_in,
                              void* d_out, int out_size, void* d_ws, size_t ws_size,
                              hipStream_t stream) {
    const float* x   = (const float*)d_in[0];
    const int* ei    = (const int*)d_in[1];
    const float* Wl1 = (const float*)d_in[2];
    const float* bl1 = (const float*)d_in[3];
    const float* Wr1 = (const float*)d_in[4];
    const float* Wl2 = (const float*)d_in[5];
    const float* bl2 = (const float*)d_in[6];
    const float* Wr2 = (const float*)d_in[7];
    const float* Wl3 = (const float*)d_in[8];
    const float* bl3 = (const float*)d_in[9];
    const float* Wr3 = (const float*)d_in[10];
    const float* Wout = (const float*)d_in[11];
    const float* bout = (const float*)d_in[12];
    float* out = (float*)d_out;

    const int* src = ei;
    const int* dst = ei + N_EDGES;

    // workspace layout (ebuf aliases hAb: ebuf dead after bucket_csr_kernel,
    // hAb first written by fused layer 1)
    char* ws = (char*)d_ws;
    unsigned* pk    = (unsigned*)ws;                           ws += (size_t)100096 * 4;
    int*   partialT = (int*)ws;                                ws += (size_t)NB * ABLK * 4;
    int*   baseT    = (int*)ws;                                ws += (size_t)NB * ABLK * 4;
    int*   tot      = (int*)ws;                                ws += 784 * 4;
    int*   bstart   = (int*)ws;                                ws += 784 * 4;
    int*   esrc     = (int*)ws;                                ws += (size_t)N_EDGES * 4;
    unsigned short* hXb   = (unsigned short*)ws;               ws += (size_t)N_NODES * 32 * 2;
    unsigned short* hAb   = (unsigned short*)ws;               ws += (size_t)N_NODES * 32 * 2;
    unsigned short* hBb   = (unsigned short*)ws;               ws += (size_t)N_NODES * 32 * 2;
    unsigned short* Wcat  = (unsigned short*)ws;               ws += 3 * 2048 * 2;
    int*   flags    = (int*)ws;                                ws += (size_t)100096 * 4;
    int*   ebuf     = (int*)hAb;    // alias

    // ---- CSR build (no global atomics) + fused prep + flag clear: 4 dispatches ----
    hist_prep_kernel<<<ABLK + CONV_BLOCKS + 24 + FLAG_BLOCKS, 256, 0, stream>>>(
        dst, partialT, x, hXb, Wl1, Wr1, Wl2, Wr2, Wl3, Wr3, Wcat, flags);
    bucket_prefix_kernel<<<(NB + 3) / 4, 256, 0, stream>>>(partialT, baseT, tot);
    bucket_scatter_kernel<<<ABLK, 256, 0, stream>>>(src, dst, baseT, tot, bstart, ebuf);
    bucket_csr_kernel<<<NB, 256, 0, stream>>>(bstart, ebuf, pk, esrc, flags);

    // ---- fused layers: 3 dispatches ----
    sage_fused_kernel<<<(N_NODES + 63) / 64, 256, 0, stream>>>(
        pk, esrc, hXb, Wcat, bl1, Wout, bout, hAb, N_NODES, 0);
    sage_fused_flag_kernel<<<(N_NODES + 63) / 64, 256, 0, stream>>>(
        pk, esrc, hAb, Wcat + 2048, bl2, hBb, flags, N_NODES);
    sage_fused_kernel<<<(N_AGENTS + 63) / 64, 256, 0, stream>>>(
        pk, esrc, hBb, Wcat + 4096, bl3, Wout, bout, out, N_AGENTS, 1);
}

// Round 7
// 174.804 us; speedup vs baseline: 2.0034x; 1.0156x over previous
//
#include <hip/hip_runtime.h>
#include <hip/hip_bf16.h>

#define N_NODES 100000
#define N_EDGES 1600000
#define N_AGENTS 1000

#define NB 782                 // buckets of 128 nodes (782*128 = 100096 >= 100000)
#define NBP 800                // padded row length for transposed partialT
#define ABLK 512               // edge-chunk blocks for histogram/scatter
#define CHUNK (N_EDGES / ABLK) // 3125 exactly
#define CONV_BLOCKS 3125       // 800000 float4->ushort4 elements / 256
#define FLAGS_I4 25024         // 100096 ints / 4
#define FLAG_BLOCKS 98         // 25024 / 256 (rounded up)

typedef short s16x8 __attribute__((ext_vector_type(8)));
typedef float f32x4 __attribute__((ext_vector_type(4)));

// float -> bf16 round-to-nearest-even
__device__ __forceinline__ unsigned short f2bf(float f) {
    unsigned u = __float_as_uint(f);
    u += 0x7fffu + ((u >> 16) & 1u);
    return (unsigned short)(u >> 16);
}
__device__ __forceinline__ float bflo(unsigned u) { return __uint_as_float(u << 16); }
__device__ __forceinline__ float bfhi(unsigned u) { return __uint_as_float(u & 0xffff0000u); }

// 8-channel accumulate of one bf16x8 row quarter
#define ACC8(U) do { \
    a0 += bflo(U.x); a1 += bfhi(U.x); \
    a2 += bflo(U.y); a3 += bfhi(U.y); \
    a4 += bflo(U.z); a5 += bfhi(U.z); \
    a6 += bflo(U.w); a7 += bfhi(U.w); } while (0)

// ---------------- A: bucket histogram (LDS atomics only) + fused prep ----------------
__global__ __launch_bounds__(256) void hist_prep_kernel(
    const int* __restrict__ dst, int* __restrict__ partialT,
    const float* __restrict__ x, unsigned short* __restrict__ xb,
    const float* __restrict__ Wl1, const float* __restrict__ Wr1,
    const float* __restrict__ Wl2, const float* __restrict__ Wr2,
    const float* __restrict__ Wl3, const float* __restrict__ Wr3,
    unsigned short* __restrict__ Wcat, int* __restrict__ flags)
{
    int b = blockIdx.x;
    if (b < ABLK) {
        __shared__ int hist[NB];
        for (int i = threadIdx.x; i < NB; i += 256) hist[i] = 0;
        __syncthreads();
        int beg = b * CHUNK;
        for (int e = beg + threadIdx.x; e < beg + CHUNK; e += 256)
            atomicAdd(&hist[dst[e] >> 7], 1);            // LDS atomic
        __syncthreads();
        // transposed: block writes its own contiguous 3KB row (coalesced, no
        // cross-XCD false sharing on partialT lines)
        for (int i = threadIdx.x; i < NB; i += 256) partialT[b * NBP + i] = hist[i];
    } else if (b < ABLK + CONV_BLOCKS) {
        int i = (b - ABLK) * 256 + threadIdx.x;          // exact: 800000 elements
        float4 v = ((const float4*)x)[i];
        ((ushort4*)xb)[i] = make_ushort4(f2bf(v.x), f2bf(v.y), f2bf(v.z), f2bf(v.w));
    } else if (b < ABLK + CONV_BLOCKS + 24) {
        int gid = (b - ABLK - CONV_BLOCKS) * 256 + threadIdx.x;  // 6144 exact
        int L = gid >> 11, idx = gid & 2047;
        int k = idx >> 5, n = idx & 31;
        const float* Wl = (L == 0) ? Wl1 : (L == 1) ? Wl2 : Wl3;
        const float* Wr = (L == 0) ? Wr1 : (L == 1) ? Wr2 : Wr3;
        float v = (k < 32) ? Wl[k * 32 + n] : Wr[(k - 32) * 32 + n];
        Wcat[gid] = f2bf(v);
    } else {
        int gid = (b - ABLK - CONV_BLOCKS - 24) * 256 + threadIdx.x;
        if (gid < FLAGS_I4) ((int4*)flags)[gid] = make_int4(0, 0, 0, 0);
    }
}

// ---------------- B1: per-bucket prefix over ABLK chunk-partials (1 wave/bucket) ----------------
__global__ __launch_bounds__(256) void bucket_prefix_kernel(
    const int* __restrict__ partialT, int* __restrict__ baseT, int* __restrict__ tot)
{
    int wave = threadIdx.x >> 6, lane = threadIdx.x & 63;
    int t = blockIdx.x * 4 + wave;
    if (t >= NB) return;
    // transposed reads: partial of chunk c for bucket t is partialT[c*NBP + t]
    int c0i = lane * 8;
    int v0 = partialT[(c0i + 0) * NBP + t];
    int v1 = partialT[(c0i + 1) * NBP + t];
    int v2 = partialT[(c0i + 2) * NBP + t];
    int v3 = partialT[(c0i + 3) * NBP + t];
    int v4 = partialT[(c0i + 4) * NBP + t];
    int v5 = partialT[(c0i + 5) * NBP + t];
    int v6 = partialT[(c0i + 6) * NBP + t];
    int v7 = partialT[(c0i + 7) * NBP + t];
    int p0 = 0, p1 = v0, p2 = p1 + v1, p3 = p2 + v2;
    int p4 = p3 + v3, p5 = p4 + v4, p6 = p5 + v5, p7 = p6 + v6;
    int s = p7 + v7;                                     // lane total
    int x = s;                                           // wave inclusive scan
    #pragma unroll
    for (int off = 1; off < 64; off <<= 1) {
        int y = __shfl_up(x, off);
        if (lane >= off) x += y;
    }
    int excl = x - s;                                    // exclusive prefix of lane sums
    int4* q = (int4*)(baseT + (size_t)t * ABLK);
    q[lane * 2]     = make_int4(excl + p0, excl + p1, excl + p2, excl + p3);
    q[lane * 2 + 1] = make_int4(excl + p4, excl + p5, excl + p6, excl + p7);
    if (lane == 63) tot[t] = x;
}

// ---------------- C: scatter edges into buckets (inlined totals-scan) ----------------
// XCD-aware chunk remap: adjacent chunks (= adjacent ebuf slots) are processed
// by blocks on the SAME XCD (blockIdx%8 heuristic), so partial-line writes to
// ebuf merge in one L2 instead of false-sharing across chiplets.
__global__ __launch_bounds__(256) void bucket_scatter_kernel(
    const int* __restrict__ src, const int* __restrict__ dst,
    const int* __restrict__ baseT, const int* __restrict__ tot,
    int* __restrict__ bstart, int* __restrict__ ebuf)
{
    __shared__ int cur[NB];
    __shared__ int tsum[256];
    int b = blockIdx.x, t = threadIdx.x;
    int chunk = ((b & 7) << 6) | (b >> 3);               // bijective on [0,512)
    int i0 = t * 4;
    int v0 = (i0     < NB) ? tot[i0]     : 0;
    int v1 = (i0 + 1 < NB) ? tot[i0 + 1] : 0;
    int v2 = (i0 + 2 < NB) ? tot[i0 + 2] : 0;
    int v3 = (i0 + 3 < NB) ? tot[i0 + 3] : 0;
    int p1 = v0, p2 = v0 + v1, p3 = v0 + v1 + v2, s4 = p3 + v3;
    tsum[t] = s4;
    __syncthreads();
    for (int off = 1; off < 256; off <<= 1) {
        int u = (t >= off) ? tsum[t - off] : 0;
        __syncthreads();
        tsum[t] += u;
        __syncthreads();
    }
    int excl = tsum[t] - s4;
    int st0 = excl, st1 = excl + p1, st2 = excl + p2, st3 = excl + p3;
    if (i0     < NB) cur[i0]     = st0 + baseT[(size_t)i0 * ABLK + chunk];
    if (i0 + 1 < NB) cur[i0 + 1] = st1 + baseT[(size_t)(i0 + 1) * ABLK + chunk];
    if (i0 + 2 < NB) cur[i0 + 2] = st2 + baseT[(size_t)(i0 + 2) * ABLK + chunk];
    if (i0 + 3 < NB) cur[i0 + 3] = st3 + baseT[(size_t)(i0 + 3) * ABLK + chunk];
    if (b == 0) {
        if (i0     < NB) bstart[i0]     = st0;
        if (i0 + 1 < NB) bstart[i0 + 1] = st1;
        if (i0 + 2 < NB) bstart[i0 + 2] = st2;
        if (i0 + 3 < NB) bstart[i0 + 3] = st3;
        if (t == 255)    bstart[NB] = tsum[255];         // == N_EDGES
    }
    __syncthreads();
    int beg = chunk * CHUNK;
    for (int e = beg + threadIdx.x; e < beg + CHUNK; e += 256) {
        int d = dst[e];
        int slot = atomicAdd(&cur[d >> 7], 1);           // LDS atomic
        ebuf[slot] = src[e] | ((d & 127) << 17);         // src < 2^17
    }
}

// ---------------- D: per-bucket CSR finalize + layer-2 active-set flagging ----------------
// Writes pk[node] = (absolute beg << 11) | degree  (beg < 2^21, deg <= 2047).
// Buckets 0..7 hold agent nodes: flag their edges' src + the agents themselves.
__global__ __launch_bounds__(256) void bucket_csr_kernel(
    const int* __restrict__ bstart, const int* __restrict__ ebuf,
    unsigned* __restrict__ pk, int* __restrict__ esrc,
    int* __restrict__ flags)
{
    __shared__ int hist4[512], cur4[512], tmp[256];
    int b = blockIdx.x;
    int t = threadIdx.x;
    int beg = bstart[b], end = bstart[b + 1];
    hist4[t] = 0; hist4[t + 256] = 0;
    __syncthreads();
    for (int i = beg + t; i < end; i += 256) {
        int p = ebuf[i];
        int ln = (p >> 17) & 127;
        int cls = (p & 0x1FFFF) >> 15;                   // 0..3
        atomicAdd(&hist4[ln * 4 + cls], 1);              // LDS atomic
    }
    __syncthreads();
    int c0 = 0, c1 = 0, c2 = 0, c3 = 0, v = 0;
    if (t < 128) {
        c0 = hist4[t * 4 + 0]; c1 = hist4[t * 4 + 1];
        c2 = hist4[t * 4 + 2]; c3 = hist4[t * 4 + 3];
        v = c0 + c1 + c2 + c3;
    }
    tmp[t] = v;
    __syncthreads();
    for (int off = 1; off < 256; off <<= 1) {
        int u = (t >= off) ? tmp[t - off] : 0;
        __syncthreads();
        tmp[t] += u;
        __syncthreads();
    }
    int excl = tmp[t] - v;                               // exclusive within bucket
    int node = b * 128 + t;
    if (t < 128 && node < N_NODES) {
        int start = beg + excl;
        pk[node] = ((unsigned)start << 11) | (unsigned)min(v, 2047);
        cur4[t * 4 + 0] = start;
        cur4[t * 4 + 1] = start + c0;
        cur4[t * 4 + 2] = start + c0 + c1;
        cur4[t * 4 + 3] = start + c0 + c1 + c2;
        if (node < N_AGENTS) flags[node] = 1;            // agents are active
    }
    __syncthreads();
    bool agent_bucket = (b < 8);                         // nodes 0..1023
    for (int i = beg + t; i < end; i += 256) {
        int p = ebuf[i];
        int ln = (p >> 17) & 127;
        int s = p & 0x1FFFF;
        int slot = atomicAdd(&cur4[ln * 4 + (s >> 15)], 1);  // LDS atomic
        esrc[slot] = s;
        if (agent_bucket && (b * 128 + ln) < N_AGENTS)
            flags[s] = 1;                                // agents' in-neighbors
    }
}

// ---------------- fused layer: aggregate (regs) -> LDS -> MFMA dense -> out ----------------
// Block = 64 nodes. Phase 1: 4 lanes/node, lane owns 8 channels, fp32 acc over
// all neighbors, 8 neighbors in flight per lane (latency hiding); pk packs
// (beg<<11|cnt). Phase 2: wave w MFMAs nodes [w*16, w*16+16); weights in LDS.
// final=1: layer-3 + 32->8 output projection through a second LDS stage.
__global__ __launch_bounds__(256) void sage_fused_kernel(
    const unsigned* __restrict__ pk, const int* __restrict__ esrc,
    const unsigned short* __restrict__ hb,
    const unsigned short* __restrict__ Wcat, const float* __restrict__ bl,
    const float* __restrict__ Wout, const float* __restrict__ bout,
    void* __restrict__ outp, int n_nodes, int final)
{
    __shared__ unsigned short sW[2048];      // 64k x 32n bf16 layer weights
    __shared__ float sb[32];
    __shared__ unsigned short smean[64 * 40];
    __shared__ float sh3[64 * 33];
    __shared__ float sWo[256];
    __shared__ float sbo[8];

    int tid = threadIdx.x;
    ((uint4*)sW)[tid] = ((const uint4*)Wcat)[tid];       // 256 x 16B = 4KB exact
    if (tid < 32) sb[tid] = bl[tid];
    if (final) {
        sWo[tid] = Wout[tid];                            // 256 exact
        if (tid < 8) sbo[tid] = bout[tid];
    }

    int lane = tid & 63, wave = tid >> 6;

    // ---- phase 1: aggregate ----
    int g = lane >> 2, q = lane & 3;
    int nodeA = blockIdx.x * 64 + wave * 16 + g;
    int beg = 0, cnt = 0;
    if (nodeA < n_nodes) {
        unsigned pkv = pk[nodeA];
        beg = (int)(pkv >> 11);
        cnt = (int)(pkv & 2047u);
    }
    int end = beg + cnt;
    float a0 = 0.f, a1 = 0.f, a2 = 0.f, a3 = 0.f;
    float a4 = 0.f, a5 = 0.f, a6 = 0.f, a7 = 0.f;
    int j = beg;
    for (; j + 7 < end; j += 8) {
        int s0 = esrc[j],     s1 = esrc[j + 1], s2 = esrc[j + 2], s3 = esrc[j + 3];
        int s4 = esrc[j + 4], s5 = esrc[j + 5], s6 = esrc[j + 6], s7 = esrc[j + 7];
        uint4 u0 = *(const uint4*)(hb + s0 * 32 + q * 8);
        uint4 u1 = *(const uint4*)(hb + s1 * 32 + q * 8);
        uint4 u2 = *(const uint4*)(hb + s2 * 32 + q * 8);
        uint4 u3 = *(const uint4*)(hb + s3 * 32 + q * 8);
        uint4 u4 = *(const uint4*)(hb + s4 * 32 + q * 8);
        uint4 u5 = *(const uint4*)(hb + s5 * 32 + q * 8);
        uint4 u6 = *(const uint4*)(hb + s6 * 32 + q * 8);
        uint4 u7 = *(const uint4*)(hb + s7 * 32 + q * 8);
        ACC8(u0); ACC8(u1); ACC8(u2); ACC8(u3);
        ACC8(u4); ACC8(u5); ACC8(u6); ACC8(u7);
    }
    for (; j + 3 < end; j += 4) {
        int s0 = esrc[j], s1 = esrc[j + 1], s2 = esrc[j + 2], s3 = esrc[j + 3];
        uint4 u0 = *(const uint4*)(hb + s0 * 32 + q * 8);
        uint4 u1 = *(const uint4*)(hb + s1 * 32 + q * 8);
        uint4 u2 = *(const uint4*)(hb + s2 * 32 + q * 8);
        uint4 u3 = *(const uint4*)(hb + s3 * 32 + q * 8);
        ACC8(u0); ACC8(u1); ACC8(u2); ACC8(u3);
    }
    for (; j < end; j++) {
        int s = esrc[j];
        uint4 u = *(const uint4*)(hb + s * 32 + q * 8);
        ACC8(u);
    }
    float iv = 1.0f / fmaxf((float)cnt, 1.0f);
    uint4 o;
    o.x = (unsigned)f2bf(a0 * iv) | ((unsigned)f2bf(a1 * iv) << 16);
    o.y = (unsigned)f2bf(a2 * iv) | ((unsigned)f2bf(a3 * iv) << 16);
    o.z = (unsigned)f2bf(a4 * iv) | ((unsigned)f2bf(a5 * iv) << 16);
    o.w = (unsigned)f2bf(a6 * iv) | ((unsigned)f2bf(a7 * iv) << 16);
    int mrow = wave * 16 + g;
    *(uint4*)&smean[mrow * 40 + q * 8] = o;
    __syncthreads();

    // ---- phase 2: dense via MFMA ----
    int l15 = lane & 15, quad = lane >> 4;
    s16x8 bf_[2][2];
    #pragma unroll
    for (int kt = 0; kt < 2; kt++)
        #pragma unroll
        for (int nt = 0; nt < 2; nt++)
            #pragma unroll
            for (int jj = 0; jj < 8; jj++) {
                int k = kt * 32 + quad * 8 + jj;
                bf_[kt][nt][jj] = (short)sW[k * 32 + l15 + nt * 16];
            }
    float bias0 = sb[l15], bias1 = sb[l15 + 16];

    int tilebase = blockIdx.x * 64 + wave * 16;
    int nodeD = tilebase + l15;
    int na = min(nodeD, n_nodes - 1);
    s16x8 am = *(const s16x8*)&smean[(wave * 16 + l15) * 40 + quad * 8];
    s16x8 as = *(const s16x8*)(hb + (size_t)na * 32 + quad * 8);
    f32x4 acc0 = {0.f, 0.f, 0.f, 0.f};
    f32x4 acc1 = {0.f, 0.f, 0.f, 0.f};
    acc0 = __builtin_amdgcn_mfma_f32_16x16x32_bf16(am, bf_[0][0], acc0, 0, 0, 0);
    acc0 = __builtin_amdgcn_mfma_f32_16x16x32_bf16(as, bf_[1][0], acc0, 0, 0, 0);
    acc1 = __builtin_amdgcn_mfma_f32_16x16x32_bf16(am, bf_[0][1], acc1, 0, 0, 0);
    acc1 = __builtin_amdgcn_mfma_f32_16x16x32_bf16(as, bf_[1][1], acc1, 0, 0, 0);

    if (!final) {
        #pragma unroll
        for (int r = 0; r < 4; r++) {
            int onode = tilebase + quad * 4 + r;
            if (onode < n_nodes) {
                ((unsigned short*)outp)[onode * 32 + l15]      = f2bf(fmaxf(acc0[r] + bias0, 0.f));
                ((unsigned short*)outp)[onode * 32 + l15 + 16] = f2bf(fmaxf(acc1[r] + bias1, 0.f));
            }
        }
    } else {
        #pragma unroll
        for (int r = 0; r < 4; r++) {
            int row = wave * 16 + quad * 4 + r;
            sh3[row * 33 + l15]      = fmaxf(acc0[r] + bias0, 0.f);
            sh3[row * 33 + l15 + 16] = fmaxf(acc1[r] + bias1, 0.f);
        }
        __syncthreads();
        // 64 nodes x 8 out-channels = 512 outputs, 2 per thread
        #pragma unroll
        for (int i = tid; i < 512; i += 256) {
            int ln = i >> 3, c = i & 7;
            int gn = blockIdx.x * 64 + ln;
            if (gn < N_AGENTS) {
                float ov = sbo[c];
                #pragma unroll
                for (int k = 0; k < 32; k++) ov += sh3[ln * 33 + k] * sWo[k * 8 + c];
                ((float*)outp)[gn * 8 + c] = ov;
            }
        }
    }
}

// ---------------- fused layer 2: flag-gated over the full grid ----------------
// Only flagged nodes aggregate and store (inactive hBb rows stay poison --
// layer 3 never reads them). ~16.6k of 100k nodes active -> ~250k edges.
__global__ __launch_bounds__(256) void sage_fused_flag_kernel(
    const unsigned* __restrict__ pk, const int* __restrict__ esrc,
    const unsigned short* __restrict__ hb,
    const unsigned short* __restrict__ Wcat, const float* __restrict__ bl,
    unsigned short* __restrict__ outp, const int* __restrict__ flags,
    int n_nodes)
{
    __shared__ unsigned short sW[2048];
    __shared__ float sb[32];
    __shared__ unsigned short smean[64 * 40];
    __shared__ int sflag[64];

    int tid = threadIdx.x;
    ((uint4*)sW)[tid] = ((const uint4*)Wcat)[tid];
    if (tid < 32) sb[tid] = bl[tid];
    if (tid < 64) {
        int gid = blockIdx.x * 64 + tid;
        sflag[tid] = (gid < n_nodes) ? flags[gid] : 0;
    }
    __syncthreads();

    int lane = tid & 63, wave = tid >> 6;

    // ---- phase 1: aggregate (flagged nodes only) ----
    int g = lane >> 2, q = lane & 3;
    int lnode = wave * 16 + g;
    int nodeA = blockIdx.x * 64 + lnode;
    int beg = 0, cnt = 0;
    if (sflag[lnode]) {
        unsigned pkv = pk[nodeA];
        beg = (int)(pkv >> 11);
        cnt = (int)(pkv & 2047u);
    }
    int end = beg + cnt;
    float a0 = 0.f, a1 = 0.f, a2 = 0.f, a3 = 0.f;
    float a4 = 0.f, a5 = 0.f, a6 = 0.f, a7 = 0.f;
    int j = beg;
    for (; j + 7 < end; j += 8) {
        int s0 = esrc[j],     s1 = esrc[j + 1], s2 = esrc[j + 2], s3 = esrc[j + 3];
        int s4 = esrc[j + 4], s5 = esrc[j + 5], s6 = esrc[j + 6], s7 = esrc[j + 7];
        uint4 u0 = *(const uint4*)(hb + s0 * 32 + q * 8);
        uint4 u1 = *(const uint4*)(hb + s1 * 32 + q * 8);
        uint4 u2 = *(const uint4*)(hb + s2 * 32 + q * 8);
        uint4 u3 = *(const uint4*)(hb + s3 * 32 + q * 8);
        uint4 u4 = *(const uint4*)(hb + s4 * 32 + q * 8);
        uint4 u5 = *(const uint4*)(hb + s5 * 32 + q * 8);
        uint4 u6 = *(const uint4*)(hb + s6 * 32 + q * 8);
        uint4 u7 = *(const uint4*)(hb + s7 * 32 + q * 8);
        ACC8(u0); ACC8(u1); ACC8(u2); ACC8(u3);
        ACC8(u4); ACC8(u5); ACC8(u6); ACC8(u7);
    }
    for (; j + 3 < end; j += 4) {
        int s0 = esrc[j], s1 = esrc[j + 1], s2 = esrc[j + 2], s3 = esrc[j + 3];
        uint4 u0 = *(const uint4*)(hb + s0 * 32 + q * 8);
        uint4 u1 = *(const uint4*)(hb + s1 * 32 + q * 8);
        uint4 u2 = *(const uint4*)(hb + s2 * 32 + q * 8);
        uint4 u3 = *(const uint4*)(hb + s3 * 32 + q * 8);
        ACC8(u0); ACC8(u1); ACC8(u2); ACC8(u3);
    }
    for (; j < end; j++) {
        int s = esrc[j];
        uint4 u = *(const uint4*)(hb + s * 32 + q * 8);
        ACC8(u);
    }
    float iv = 1.0f / fmaxf((float)cnt, 1.0f);
    uint4 o;
    o.x = (unsigned)f2bf(a0 * iv) | ((unsigned)f2bf(a1 * iv) << 16);
    o.y = (unsigned)f2bf(a2 * iv) | ((unsigned)f2bf(a3 * iv) << 16);
    o.z = (unsigned)f2bf(a4 * iv) | ((unsigned)f2bf(a5 * iv) << 16);
    o.w = (unsigned)f2bf(a6 * iv) | ((unsigned)f2bf(a7 * iv) << 16);
    *(uint4*)&smean[lnode * 40 + q * 8] = o;
    __syncthreads();

    // ---- phase 2: dense via MFMA ----
    int l15 = lane & 15, quad = lane >> 4;
    s16x8 bf_[2][2];
    #pragma unroll
    for (int kt = 0; kt < 2; kt++)
        #pragma unroll
        for (int nt = 0; nt < 2; nt++)
            #pragma unroll
            for (int jj = 0; jj < 8; jj++) {
                int k = kt * 32 + quad * 8 + jj;
                bf_[kt][nt][jj] = (short)sW[k * 32 + l15 + nt * 16];
            }
    float bias0 = sb[l15], bias1 = sb[l15 + 16];

    int tilebase = blockIdx.x * 64 + wave * 16;
    int nodeD = tilebase + l15;
    int na = min(nodeD, n_nodes - 1);
    s16x8 am = *(const s16x8*)&smean[(wave * 16 + l15) * 40 + quad * 8];
    s16x8 as = *(const s16x8*)(hb + (size_t)na * 32 + quad * 8);
    f32x4 acc0 = {0.f, 0.f, 0.f, 0.f};
    f32x4 acc1 = {0.f, 0.f, 0.f, 0.f};
    acc0 = __builtin_amdgcn_mfma_f32_16x16x32_bf16(am, bf_[0][0], acc0, 0, 0, 0);
    acc0 = __builtin_amdgcn_mfma_f32_16x16x32_bf16(as, bf_[1][0], acc0, 0, 0, 0);
    acc1 = __builtin_amdgcn_mfma_f32_16x16x32_bf16(am, bf_[0][1], acc1, 0, 0, 0);
    acc1 = __builtin_amdgcn_mfma_f32_16x16x32_bf16(as, bf_[1][1], acc1, 0, 0, 0);

    #pragma unroll
    for (int r = 0; r < 4; r++) {
        int lr = wave * 16 + quad * 4 + r;
        int onode = tilebase + quad * 4 + r;
        if (onode < n_nodes && sflag[lr]) {
            outp[onode * 32 + l15]      = f2bf(fmaxf(acc0[r] + bias0, 0.f));
            outp[onode * 32 + l15 + 16] = f2bf(fmaxf(acc1[r] + bias1, 0.f));
        }
    }
}

extern "C" void kernel_launch(void* const* d_in, const int* in_sizes, int n_in,
                              void* d_out, int out_size, void* d_ws, size_t ws_size,
                              hipStream_t stream) {
    const float* x   = (const float*)d_in[0];
    const int* ei    = (const int*)d_in[1];
    const float* Wl1 = (const float*)d_in[2];
    const float* bl1 = (const float*)d_in[3];
    const float* Wr1 = (const float*)d_in[4];
    const float* Wl2 = (const float*)d_in[5];
    const float* bl2 = (const float*)d_in[6];
    const float* Wr2 = (const float*)d_in[7];
    const float* Wl3 = (const float*)d_in[8];
    const float* bl3 = (const float*)d_in[9];
    const float* Wr3 = (const float*)d_in[10];
    const float* Wout = (const float*)d_in[11];
    const float* bout = (const float*)d_in[12];
    float* out = (float*)d_out;

    const int* src = ei;
    const int* dst = ei + N_EDGES;

    // workspace layout (ebuf aliases hAb: ebuf dead after bucket_csr_kernel,
    // hAb first written by fused layer 1)
    char* ws = (char*)d_ws;
    unsigned* pk    = (unsigned*)ws;                           ws += (size_t)100096 * 4;
    int*   partialT = (int*)ws;                                ws += (size_t)ABLK * NBP * 4;
    int*   baseT    = (int*)ws;                                ws += (size_t)NB * ABLK * 4;
    int*   tot      = (int*)ws;                                ws += 784 * 4;
    int*   bstart   = (int*)ws;                                ws += 784 * 4;
    int*   esrc     = (int*)ws;                                ws += (size_t)N_EDGES * 4;
    unsigned short* hXb   = (unsigned short*)ws;               ws += (size_t)N_NODES * 32 * 2;
    unsigned short* hAb   = (unsigned short*)ws;               ws += (size_t)N_NODES * 32 * 2;
    unsigned short* hBb   = (unsigned short*)ws;               ws += (size_t)N_NODES * 32 * 2;
    unsigned short* Wcat  = (unsigned short*)ws;               ws += 3 * 2048 * 2;
    int*   flags    = (int*)ws;                                ws += (size_t)100096 * 4;
    int*   ebuf     = (int*)hAb;    // alias

    // ---- CSR build (no global atomics) + fused prep + flag clear: 4 dispatches ----
    hist_prep_kernel<<<ABLK + CONV_BLOCKS + 24 + FLAG_BLOCKS, 256, 0, stream>>>(
        dst, partialT, x, hXb, Wl1, Wr1, Wl2, Wr2, Wl3, Wr3, Wcat, flags);
    bucket_prefix_kernel<<<(NB + 3) / 4, 256, 0, stream>>>(partialT, baseT, tot);
    bucket_scatter_kernel<<<ABLK, 256, 0, stream>>>(src, dst, baseT, tot, bstart, ebuf);
    bucket_csr_kernel<<<NB, 256, 0, stream>>>(bstart, ebuf, pk, esrc, flags);

    // ---- fused layers: 3 dispatches ----
    sage_fused_kernel<<<(N_NODES + 63) / 64, 256, 0, stream>>>(
        pk, esrc, hXb, Wcat, bl1, Wout, bout, hAb, N_NODES, 0);
    sage_fused_flag_kernel<<<(N_NODES + 63) / 64, 256, 0, stream>>>(
        pk, esrc, hAb, Wcat + 2048, bl2, hBb, flags, N_NODES);
    sage_fused_kernel<<<(N_AGENTS + 63) / 64, 256, 0, stream>>>(
        pk, esrc, hBb, Wcat + 4096, bl3, Wout, bout, out, N_AGENTS, 1);
}